// Round 3
// baseline (226.233 us; speedup 1.0000x reference)
//
#include <hip/hip_runtime.h>

// FastSAM3DPromptEncoder: out[b,n,c] = pos_embed[0,c,z,y,x] + point_emb[labels[b,n],c]
// (z,y,x) = clamp(trunc(points[b,n,:]), 0, 63).
//
// Counting-sort points by 64-B-line key (z,y,x>>4); gather with lane=slot so
// each wave-load coalesces to ~8 line requests (slots sharing a line merge).

constexpr int B_ = 32;
constexpr int N_ = 4096;
constexpr int C_ = 256;
constexpr int GD = 64;
constexpr int PTS = B_ * N_;            // 131072
constexpr int CELLS = GD * GD * GD;     // 262144 (channel stride)
constexpr int NBINS = GD * GD * (GD / 16); // 16384 line keys

__device__ __forceinline__ int clamp63(float v) {
    int i = (int)v;
    return min(max(i, 0), GD - 1);
}

// ---- K0: zero histogram ----
__global__ __launch_bounds__(256) void k_zero(unsigned* __restrict__ hist) {
    int t = blockIdx.x * blockDim.x + threadIdx.x;
    if (t < NBINS) hist[t] = 0u;
}

// ---- K1: histogram of line keys ----
__global__ __launch_bounds__(256) void k_hist(const float* __restrict__ points,
                                              unsigned* __restrict__ hist) {
    int p = blockIdx.x * blockDim.x + threadIdx.x;
    if (p >= PTS) return;
    int zi = clamp63(points[p * 3 + 0]);
    int yi = clamp63(points[p * 3 + 1]);
    int xi = clamp63(points[p * 3 + 2]);
    int key = (zi << 8) | (yi << 2) | (xi >> 4);
    atomicAdd(&hist[key], 1u);
}

// ---- K2: exclusive prefix sum over 16384 bins (single block) ----
__global__ __launch_bounds__(1024) void k_scan(const unsigned* __restrict__ hist,
                                               unsigned* __restrict__ cursor) {
    __shared__ unsigned sums[1024];
    const int t = threadIdx.x;
    unsigned h[16];
    unsigned s = 0;
    #pragma unroll
    for (int i = 0; i < 16; ++i) { h[i] = hist[t * 16 + i]; s += h[i]; }
    sums[t] = s;
    __syncthreads();
    for (int off = 1; off < 1024; off <<= 1) {
        unsigned v = (t >= off) ? sums[t - off] : 0u;
        __syncthreads();
        sums[t] += v;
        __syncthreads();
    }
    unsigned run = (t > 0) ? sums[t - 1] : 0u;
    #pragma unroll
    for (int i = 0; i < 16; ++i) { cursor[t * 16 + i] = run; run += h[i]; }
}

// ---- K3: scatter points into sorted slots ----
__global__ __launch_bounds__(256) void k_scatter(const float* __restrict__ points,
                                                 const int* __restrict__ labels,
                                                 unsigned* __restrict__ cursor,
                                                 unsigned* __restrict__ rec_cell,
                                                 unsigned* __restrict__ rec_p) {
    int p = blockIdx.x * blockDim.x + threadIdx.x;
    if (p >= PTS) return;
    int zi = clamp63(points[p * 3 + 0]);
    int yi = clamp63(points[p * 3 + 1]);
    int xi = clamp63(points[p * 3 + 2]);
    int key  = (zi << 8) | (yi << 2) | (xi >> 4);
    int cell = (zi << 12) | (yi << 6) | xi;
    unsigned slot = atomicAdd(&cursor[key], 1u);
    rec_cell[slot] = (unsigned)cell | ((unsigned)labels[p] << 18);
    rec_p[slot]    = (unsigned)p;
}

// ---- K4: gather, lane = sorted slot, loop over 64 channel-groups of 4 ----
__global__ __launch_bounds__(256) void k_gather(const unsigned* __restrict__ rec_cell,
                                                const unsigned* __restrict__ rec_p,
                                                const float* __restrict__ pos,
                                                const float* __restrict__ pemb,
                                                float* __restrict__ out) {
    // XCD-chunked swizzle keeps contiguous sorted ranges on one XCD's L2.
    const int nb  = gridDim.x;              // multiple of 8
    const int b   = blockIdx.x;
    const int swz = (b & 7) * (nb >> 3) + (b >> 3);
    const int slot = swz * 256 + threadIdx.x;   // 256 consecutive slots per block

    const unsigned rc = rec_cell[slot];     // coalesced per-lane load
    const unsigned p  = rec_p[slot];
    const unsigned cell = rc & 0x3FFFFu;
    const unsigned lab  = rc >> 18;

    const float* g      = pos + cell;            // per-lane base; lanes share lines
    const float* te_row = pemb + lab * C_;
    float*       orow   = out + (size_t)p * C_;

    #pragma unroll 4
    for (int cg = 0; cg < 64; ++cg) {
        const int c4 = cg << 2;
        const float4 te = *reinterpret_cast<const float4*>(te_row + c4);
        float4 r;
        r.x = g[(size_t)(c4 + 0) * CELLS] + te.x;
        r.y = g[(size_t)(c4 + 1) * CELLS] + te.y;
        r.z = g[(size_t)(c4 + 2) * CELLS] + te.z;
        r.w = g[(size_t)(c4 + 3) * CELLS] + te.w;
        *reinterpret_cast<float4*>(orow + c4) = r;   // 16-B scatter store per lane
    }
}

// ---- fallback if ws too small ----
__global__ __launch_bounds__(256) void k_naive(const float* __restrict__ points,
                                               const int* __restrict__ labels,
                                               const float* __restrict__ pos,
                                               const float* __restrict__ pemb,
                                               float* __restrict__ out) {
    const int t    = blockIdx.x * blockDim.x + threadIdx.x;
    const int p    = t >> 6;
    const int lane = t & 63;
    const int c4   = lane << 2;
    if (p >= PTS) return;
    int zi = clamp63(points[p * 3 + 0]);
    int yi = clamp63(points[p * 3 + 1]);
    int xi = clamp63(points[p * 3 + 2]);
    const int cell = (zi << 12) | (yi << 6) | xi;
    const int lab  = labels[p];
    const float4 te = *reinterpret_cast<const float4*>(pemb + lab * C_ + c4);
    const float* g = pos + cell;
    float4 r;
    r.x = g[(c4 + 0) * CELLS] + te.x;
    r.y = g[(c4 + 1) * CELLS] + te.y;
    r.z = g[(c4 + 2) * CELLS] + te.z;
    r.w = g[(c4 + 3) * CELLS] + te.w;
    *reinterpret_cast<float4*>(out + p * C_ + c4) = r;
}

extern "C" void kernel_launch(void* const* d_in, const int* in_sizes, int n_in,
                              void* d_out, int out_size, void* d_ws, size_t ws_size,
                              hipStream_t stream) {
    const float* points = (const float*)d_in[0];
    const int*   labels = (const int*)d_in[1];
    const float* pos    = (const float*)d_in[2];
    const float* pemb   = (const float*)d_in[3];
    float*       out    = (float*)d_out;

    const size_t need = (size_t)(NBINS * 2 + PTS * 2) * sizeof(unsigned);
    if (ws_size < need) {
        const int total = PTS * 64;
        k_naive<<<(total + 255) / 256, 256, 0, stream>>>(points, labels, pos, pemb, out);
        return;
    }
    unsigned* hist     = (unsigned*)d_ws;
    unsigned* cursor   = hist + NBINS;
    unsigned* rec_cell = cursor + NBINS;
    unsigned* rec_p    = rec_cell + PTS;

    k_zero<<<(NBINS + 255) / 256, 256, 0, stream>>>(hist);
    k_hist<<<(PTS + 255) / 256, 256, 0, stream>>>(points, hist);
    k_scan<<<1, 1024, 0, stream>>>(hist, cursor);
    k_scatter<<<(PTS + 255) / 256, 256, 0, stream>>>(points, labels, cursor, rec_cell, rec_p);
    k_gather<<<PTS / 256, 256, 0, stream>>>(rec_cell, rec_p, pos, pemb, out);
}

// Round 4
// 142.559 us; speedup vs baseline: 1.5869x; 1.5869x over previous
//
#include <hip/hip_runtime.h>

// FastSAM3DPromptEncoder: out[b,n,c] = pos_embed[0,c,z,y,x] + point_emb[labels[b,n],c]
// (z,y,x) = clamp(trunc(points[b,n,:]), 0, 63).
//
// Counting-sort points by 64-B-line key (z,y,x>>4). Gather with lane=slot
// (sorted slots share cache lines -> HW coalescer merges ~8 lanes/line) and
// channel dimension split across blocks to keep occupancy high.

constexpr int B_ = 32;
constexpr int N_ = 4096;
constexpr int C_ = 256;
constexpr int GD = 64;
constexpr int PTS = B_ * N_;            // 131072
constexpr int CELLS = GD * GD * GD;     // 262144 (channel stride)
constexpr int NBINS = GD * GD * (GD / 16); // 16384 line keys
constexpr int CSPLIT = 8;               // channel-group chunks per slot-range
constexpr int SLOTBLKS = PTS / 256;     // 512

__device__ __forceinline__ int clamp63(float v) {
    int i = (int)v;
    return min(max(i, 0), GD - 1);
}

// ---- K0: zero histogram ----
__global__ __launch_bounds__(256) void k_zero(unsigned* __restrict__ hist) {
    int t = blockIdx.x * blockDim.x + threadIdx.x;
    if (t < NBINS) hist[t] = 0u;
}

// ---- K1: histogram of line keys ----
__global__ __launch_bounds__(256) void k_hist(const float* __restrict__ points,
                                              unsigned* __restrict__ hist) {
    int p = blockIdx.x * blockDim.x + threadIdx.x;
    if (p >= PTS) return;
    int zi = clamp63(points[p * 3 + 0]);
    int yi = clamp63(points[p * 3 + 1]);
    int xi = clamp63(points[p * 3 + 2]);
    int key = (zi << 8) | (yi << 2) | (xi >> 4);
    atomicAdd(&hist[key], 1u);
}

// ---- K2: exclusive prefix sum over 16384 bins (single block) ----
__global__ __launch_bounds__(1024) void k_scan(const unsigned* __restrict__ hist,
                                               unsigned* __restrict__ cursor) {
    __shared__ unsigned sums[1024];
    const int t = threadIdx.x;
    unsigned h[16];
    unsigned s = 0;
    #pragma unroll
    for (int i = 0; i < 16; ++i) { h[i] = hist[t * 16 + i]; s += h[i]; }
    sums[t] = s;
    __syncthreads();
    for (int off = 1; off < 1024; off <<= 1) {
        unsigned v = (t >= off) ? sums[t - off] : 0u;
        __syncthreads();
        sums[t] += v;
        __syncthreads();
    }
    unsigned run = (t > 0) ? sums[t - 1] : 0u;
    #pragma unroll
    for (int i = 0; i < 16; ++i) { cursor[t * 16 + i] = run; run += h[i]; }
}

// ---- K3: scatter points into sorted slots ----
__global__ __launch_bounds__(256) void k_scatter(const float* __restrict__ points,
                                                 const int* __restrict__ labels,
                                                 unsigned* __restrict__ cursor,
                                                 unsigned* __restrict__ rec_cell,
                                                 unsigned* __restrict__ rec_p) {
    int p = blockIdx.x * blockDim.x + threadIdx.x;
    if (p >= PTS) return;
    int zi = clamp63(points[p * 3 + 0]);
    int yi = clamp63(points[p * 3 + 1]);
    int xi = clamp63(points[p * 3 + 2]);
    int key  = (zi << 8) | (yi << 2) | (xi >> 4);
    int cell = (zi << 12) | (yi << 6) | xi;
    unsigned slot = atomicAdd(&cursor[key], 1u);
    rec_cell[slot] = (unsigned)cell | ((unsigned)labels[p] << 18);
    rec_p[slot]    = (unsigned)p;
}

// ---- K4: gather. lane = sorted slot; 8 channel-groups per block ----
__global__ __launch_bounds__(256) void k_gather(const unsigned* __restrict__ rec_cell,
                                                const unsigned* __restrict__ rec_p,
                                                const float* __restrict__ pos,
                                                const float* __restrict__ pemb,
                                                float* __restrict__ out) {
    const int bc = blockIdx.x;
    const int sb = bc & (SLOTBLKS - 1);     // slot-block 0..511
    const int cb = bc >> 9;                  // channel-chunk 0..7
    // XCD-chunked swizzle on the slot-block axis: each XCD owns a contiguous
    // sorted-slot range -> its L2 sees a compact region of pos_embed.
    const int swz = (sb & 7) * (SLOTBLKS >> 3) + (sb >> 3);
    const int slot = swz * 256 + threadIdx.x;

    const unsigned rc = rec_cell[slot];     // coalesced
    const unsigned p  = rec_p[slot];
    const unsigned cell = rc & 0x3FFFFu;
    const unsigned lab  = rc >> 18;

    const float* g      = pos + cell + (size_t)(cb * 32) * CELLS;
    const float* te_row = pemb + lab * C_ + cb * 32;
    float*       orow   = out + (size_t)p * C_ + cb * 32;

    #pragma unroll
    for (int cg = 0; cg < 8; ++cg) {
        const int c4 = cg << 2;
        const float4 te = *reinterpret_cast<const float4*>(te_row + c4);
        float4 r;
        r.x = g[(size_t)(c4 + 0) * CELLS] + te.x;
        r.y = g[(size_t)(c4 + 1) * CELLS] + te.y;
        r.z = g[(size_t)(c4 + 2) * CELLS] + te.z;
        r.w = g[(size_t)(c4 + 3) * CELLS] + te.w;
        *reinterpret_cast<float4*>(orow + c4) = r;
    }
}

// ---- fallback if ws too small ----
__global__ __launch_bounds__(256) void k_naive(const float* __restrict__ points,
                                               const int* __restrict__ labels,
                                               const float* __restrict__ pos,
                                               const float* __restrict__ pemb,
                                               float* __restrict__ out) {
    const int t    = blockIdx.x * blockDim.x + threadIdx.x;
    const int p    = t >> 6;
    const int lane = t & 63;
    const int c4   = lane << 2;
    if (p >= PTS) return;
    int zi = clamp63(points[p * 3 + 0]);
    int yi = clamp63(points[p * 3 + 1]);
    int xi = clamp63(points[p * 3 + 2]);
    const int cell = (zi << 12) | (yi << 6) | xi;
    const int lab  = labels[p];
    const float4 te = *reinterpret_cast<const float4*>(pemb + lab * C_ + c4);
    const float* g = pos + cell;
    float4 r;
    r.x = g[(c4 + 0) * CELLS] + te.x;
    r.y = g[(c4 + 1) * CELLS] + te.y;
    r.z = g[(c4 + 2) * CELLS] + te.z;
    r.w = g[(c4 + 3) * CELLS] + te.w;
    *reinterpret_cast<float4*>(out + p * C_ + c4) = r;
}

extern "C" void kernel_launch(void* const* d_in, const int* in_sizes, int n_in,
                              void* d_out, int out_size, void* d_ws, size_t ws_size,
                              hipStream_t stream) {
    const float* points = (const float*)d_in[0];
    const int*   labels = (const int*)d_in[1];
    const float* pos    = (const float*)d_in[2];
    const float* pemb   = (const float*)d_in[3];
    float*       out    = (float*)d_out;

    const size_t need = (size_t)(NBINS * 2 + PTS * 2) * sizeof(unsigned);
    if (ws_size < need) {
        const int total = PTS * 64;
        k_naive<<<(total + 255) / 256, 256, 0, stream>>>(points, labels, pos, pemb, out);
        return;
    }
    unsigned* hist     = (unsigned*)d_ws;
    unsigned* cursor   = hist + NBINS;
    unsigned* rec_cell = cursor + NBINS;
    unsigned* rec_p    = rec_cell + PTS;

    k_zero<<<(NBINS + 255) / 256, 256, 0, stream>>>(hist);
    k_hist<<<(PTS + 255) / 256, 256, 0, stream>>>(points, hist);
    k_scan<<<1, 1024, 0, stream>>>(hist, cursor);
    k_scatter<<<(PTS + 255) / 256, 256, 0, stream>>>(points, labels, cursor, rec_cell, rec_p);
    k_gather<<<SLOTBLKS * CSPLIT, 256, 0, stream>>>(rec_cell, rec_p, pos, pemb, out);
}

// Round 5
// 138.467 us; speedup vs baseline: 1.6338x; 1.0296x over previous
//
#include <hip/hip_runtime.h>

// FastSAM3DPromptEncoder: out[b,n,c] = pos_embed[0,c,z,y,x] + point_emb[labels[b,n],c]
// (z,y,x) = clamp(trunc(points[b,n,:]), 0, 63).
//
// Counting-sort points by 64-B-line key (z,y,x>>4) -> bin-centric gather:
// one block per bin stages the bin's [16 x-cells][256 ch] tile into LDS with
// dense float4 loads (each (line,channel) fetched exactly once grid-wide),
// then writes each point's 1-KB output row as one fully-coalesced wave store.

constexpr int B_ = 32;
constexpr int N_ = 4096;
constexpr int C_ = 256;
constexpr int GD = 64;
constexpr int PTS = B_ * N_;               // 131072
constexpr int CELLS = GD * GD * GD;        // 262144 (channel stride)
constexpr int NBINS = GD * GD * (GD / 16); // 16384 line keys

__device__ __forceinline__ int clamp63(float v) {
    int i = (int)v;
    return min(max(i, 0), GD - 1);
}

// ---- K0: zero histogram ----
__global__ __launch_bounds__(256) void k_zero(unsigned* __restrict__ hist) {
    int t = blockIdx.x * blockDim.x + threadIdx.x;
    if (t < NBINS) hist[t] = 0u;
}

// ---- K1: histogram of line keys ----
__global__ __launch_bounds__(256) void k_hist(const float* __restrict__ points,
                                              unsigned* __restrict__ hist) {
    int p = blockIdx.x * blockDim.x + threadIdx.x;
    if (p >= PTS) return;
    int zi = clamp63(points[p * 3 + 0]);
    int yi = clamp63(points[p * 3 + 1]);
    int xi = clamp63(points[p * 3 + 2]);
    int key = (zi << 8) | (yi << 2) | (xi >> 4);
    atomicAdd(&hist[key], 1u);
}

// ---- K2: exclusive prefix sum over 16384 bins (single block);
//      writes mutable cursor + read-only bin_ofs (incl. total at [NBINS]) ----
__global__ __launch_bounds__(1024) void k_scan(const unsigned* __restrict__ hist,
                                               unsigned* __restrict__ cursor,
                                               unsigned* __restrict__ bin_ofs) {
    __shared__ unsigned sums[1024];
    const int t = threadIdx.x;
    unsigned h[16];
    unsigned s = 0;
    #pragma unroll
    for (int i = 0; i < 16; ++i) { h[i] = hist[t * 16 + i]; s += h[i]; }
    sums[t] = s;
    __syncthreads();
    for (int off = 1; off < 1024; off <<= 1) {
        unsigned v = (t >= off) ? sums[t - off] : 0u;
        __syncthreads();
        sums[t] += v;
        __syncthreads();
    }
    unsigned run = (t > 0) ? sums[t - 1] : 0u;
    #pragma unroll
    for (int i = 0; i < 16; ++i) {
        cursor[t * 16 + i]  = run;
        bin_ofs[t * 16 + i] = run;
        run += h[i];
    }
    if (t == 1023) bin_ofs[NBINS] = sums[1023];
}

// ---- K3: scatter packed point records into sorted slots ----
// rec = p (17b) | lab (1b @17) | x&15 (4b @18)
__global__ __launch_bounds__(256) void k_scatter(const float* __restrict__ points,
                                                 const int* __restrict__ labels,
                                                 unsigned* __restrict__ cursor,
                                                 unsigned* __restrict__ recs) {
    int p = blockIdx.x * blockDim.x + threadIdx.x;
    if (p >= PTS) return;
    int zi = clamp63(points[p * 3 + 0]);
    int yi = clamp63(points[p * 3 + 1]);
    int xi = clamp63(points[p * 3 + 2]);
    int key = (zi << 8) | (yi << 2) | (xi >> 4);
    unsigned slot = atomicAdd(&cursor[key], 1u);
    recs[slot] = (unsigned)p | ((unsigned)labels[p] << 17) | ((unsigned)(xi & 15) << 18);
}

// ---- K4: bin-centric gather. One block per bin. ----
__global__ __launch_bounds__(256) void k_gather(const unsigned* __restrict__ bin_ofs,
                                                const unsigned* __restrict__ recs,
                                                const float* __restrict__ pos,
                                                const float* __restrict__ pemb,
                                                float* __restrict__ out) {
    const int bin = blockIdx.x;
    const unsigned start = bin_ofs[bin];
    const unsigned end   = bin_ofs[bin + 1];
    if (start == end) return;   // empty bin (~0.03% of bins)

    __shared__ float tile[16 * C_];          // [o][c] : 16 KB

    // linebase: first cell of this bin's 16-cell x-run
    const int zi = bin >> 8;
    const int yi = (bin >> 2) & 63;
    const int xh = bin & 3;
    const size_t linebase = ((size_t)zi << 12) | ((size_t)yi << 6) | ((size_t)xh << 4);

    // Phase 1: stage [16][256] tile. Dense float4 loads: thread covers
    // (channel c = q>>2, x-offset o = (q&3)*4 .. +3). Every byte consumed.
    #pragma unroll
    for (int r = 0; r < 4; ++r) {
        const int q  = r * 256 + threadIdx.x;   // 0..1023 float4s
        const int c  = q >> 2;
        const int o4 = (q & 3) << 2;
        const float4 v = *reinterpret_cast<const float4*>(
            pos + (size_t)c * CELLS + linebase + o4);
        tile[(o4 + 0) * C_ + c] = v.x;
        tile[(o4 + 1) * C_ + c] = v.y;
        tile[(o4 + 2) * C_ + c] = v.z;
        tile[(o4 + 3) * C_ + c] = v.w;
    }
    __syncthreads();

    // Phase 2: one wave per point; 64 lanes x float4 = coalesced 1-KB row.
    const int w = threadIdx.x >> 6;
    const int l = threadIdx.x & 63;
    const float4* tile4 = reinterpret_cast<const float4*>(tile);

    for (unsigned i = start + w; i < end; i += 4) {
        const unsigned rec = recs[i];            // wave-uniform broadcast
        const unsigned p   = rec & 0x1FFFFu;
        const unsigned lab = (rec >> 17) & 1u;
        const unsigned o   = rec >> 18;
        const float4 v  = tile4[o * 64 + l];     // contiguous 1-KB ds_read
        const float4 te = *reinterpret_cast<const float4*>(pemb + lab * C_ + 4 * l);
        float4 rr;
        rr.x = v.x + te.x; rr.y = v.y + te.y; rr.z = v.z + te.z; rr.w = v.w + te.w;
        *reinterpret_cast<float4*>(out + (size_t)p * C_ + 4 * l) = rr;
    }
}

// ---- fallback if ws too small ----
__global__ __launch_bounds__(256) void k_naive(const float* __restrict__ points,
                                               const int* __restrict__ labels,
                                               const float* __restrict__ pos,
                                               const float* __restrict__ pemb,
                                               float* __restrict__ out) {
    const int t    = blockIdx.x * blockDim.x + threadIdx.x;
    const int p    = t >> 6;
    const int lane = t & 63;
    const int c4   = lane << 2;
    if (p >= PTS) return;
    int zi = clamp63(points[p * 3 + 0]);
    int yi = clamp63(points[p * 3 + 1]);
    int xi = clamp63(points[p * 3 + 2]);
    const int cell = (zi << 12) | (yi << 6) | xi;
    const int lab  = labels[p];
    const float4 te = *reinterpret_cast<const float4*>(pemb + lab * C_ + c4);
    const float* g = pos + cell;
    float4 r;
    r.x = g[(c4 + 0) * CELLS] + te.x;
    r.y = g[(c4 + 1) * CELLS] + te.y;
    r.z = g[(c4 + 2) * CELLS] + te.z;
    r.w = g[(c4 + 3) * CELLS] + te.w;
    *reinterpret_cast<float4*>(out + p * C_ + c4) = r;
}

extern "C" void kernel_launch(void* const* d_in, const int* in_sizes, int n_in,
                              void* d_out, int out_size, void* d_ws, size_t ws_size,
                              hipStream_t stream) {
    const float* points = (const float*)d_in[0];
    const int*   labels = (const int*)d_in[1];
    const float* pos    = (const float*)d_in[2];
    const float* pemb   = (const float*)d_in[3];
    float*       out    = (float*)d_out;

    // ws layout: hist[NBINS] | cursor[NBINS] | bin_ofs[NBINS+1] | recs[PTS]
    const size_t need = (size_t)(NBINS * 3 + 1 + PTS) * sizeof(unsigned);
    if (ws_size < need) {
        const int total = PTS * 64;
        k_naive<<<(total + 255) / 256, 256, 0, stream>>>(points, labels, pos, pemb, out);
        return;
    }
    unsigned* hist    = (unsigned*)d_ws;
    unsigned* cursor  = hist + NBINS;
    unsigned* bin_ofs = cursor + NBINS;
    unsigned* recs    = bin_ofs + NBINS + 1;

    k_zero<<<(NBINS + 255) / 256, 256, 0, stream>>>(hist);
    k_hist<<<(PTS + 255) / 256, 256, 0, stream>>>(points, hist);
    k_scan<<<1, 1024, 0, stream>>>(hist, cursor, bin_ofs);
    k_scatter<<<(PTS + 255) / 256, 256, 0, stream>>>(points, labels, cursor, recs);
    k_gather<<<NBINS, 256, 0, stream>>>(bin_ofs, recs, pos, pemb, out);
}

// Round 7
// 108.824 us; speedup vs baseline: 2.0789x; 1.2724x over previous
//
#include <hip/hip_runtime.h>

// FastSAM3DPromptEncoder: out[b,n,c] = pos_embed[0,c,z,y,x] + point_emb[labels[b,n],c]
// (z,y,x) = clamp(trunc(points[b,n,:]), 0, 63).
//
// Counting-sort points by 64-B-line key (z,y,x>>4) -> bin-centric gather.
// 8 bins per block, double-buffered LDS tile, software-pipelined staging
// (issue next bin's loads before the barrier, ds_write after phase-2) so HBM
// latency hides under compute. Padded LDS stride (260) = conflict-free.

constexpr int B_ = 32;
constexpr int N_ = 4096;
constexpr int C_ = 256;
constexpr int GD = 64;
constexpr int PTS = B_ * N_;               // 131072
constexpr int CELLS = GD * GD * GD;        // 262144 (channel stride)
constexpr int NBINS = GD * GD * (GD / 16); // 16384 line keys
constexpr int BPB = 8;                     // bins per block
constexpr int NBLK = NBINS / BPB;          // 2048 blocks
constexpr int TP = 260;                    // padded tile row stride (floats)

typedef float f32x4 __attribute__((ext_vector_type(4)));  // native vec for nt-store

__device__ __forceinline__ int clamp63(float v) {
    int i = (int)v;
    return min(max(i, 0), GD - 1);
}

// ---- K0: zero histogram ----
__global__ __launch_bounds__(256) void k_zero(unsigned* __restrict__ hist) {
    int t = blockIdx.x * blockDim.x + threadIdx.x;
    if (t < NBINS) hist[t] = 0u;
}

// ---- K1: histogram of line keys ----
__global__ __launch_bounds__(256) void k_hist(const float* __restrict__ points,
                                              unsigned* __restrict__ hist) {
    int p = blockIdx.x * blockDim.x + threadIdx.x;
    if (p >= PTS) return;
    int zi = clamp63(points[p * 3 + 0]);
    int yi = clamp63(points[p * 3 + 1]);
    int xi = clamp63(points[p * 3 + 2]);
    int key = (zi << 8) | (yi << 2) | (xi >> 4);
    atomicAdd(&hist[key], 1u);
}

// ---- K2: exclusive prefix sum over 16384 bins (single block) ----
__global__ __launch_bounds__(1024) void k_scan(const unsigned* __restrict__ hist,
                                               unsigned* __restrict__ cursor,
                                               unsigned* __restrict__ bin_ofs) {
    __shared__ unsigned sums[1024];
    const int t = threadIdx.x;
    unsigned h[16];
    unsigned s = 0;
    #pragma unroll
    for (int i = 0; i < 16; ++i) { h[i] = hist[t * 16 + i]; s += h[i]; }
    sums[t] = s;
    __syncthreads();
    for (int off = 1; off < 1024; off <<= 1) {
        unsigned v = (t >= off) ? sums[t - off] : 0u;
        __syncthreads();
        sums[t] += v;
        __syncthreads();
    }
    unsigned run = (t > 0) ? sums[t - 1] : 0u;
    #pragma unroll
    for (int i = 0; i < 16; ++i) {
        cursor[t * 16 + i]  = run;
        bin_ofs[t * 16 + i] = run;
        run += h[i];
    }
    if (t == 1023) bin_ofs[NBINS] = sums[1023];
}

// ---- K3: scatter packed point records into sorted slots ----
// rec = p (17b) | lab (1b @17) | x&15 (4b @18)
__global__ __launch_bounds__(256) void k_scatter(const float* __restrict__ points,
                                                 const int* __restrict__ labels,
                                                 unsigned* __restrict__ cursor,
                                                 unsigned* __restrict__ recs) {
    int p = blockIdx.x * blockDim.x + threadIdx.x;
    if (p >= PTS) return;
    int zi = clamp63(points[p * 3 + 0]);
    int yi = clamp63(points[p * 3 + 1]);
    int xi = clamp63(points[p * 3 + 2]);
    int key = (zi << 8) | (yi << 2) | (xi >> 4);
    unsigned slot = atomicAdd(&cursor[key], 1u);
    recs[slot] = (unsigned)p | ((unsigned)labels[p] << 17) | ((unsigned)(xi & 15) << 18);
}

// ---- K4: pipelined bin-centric gather. 8 bins/block, dbuf LDS ----
__global__ __launch_bounds__(256) void k_gather(const unsigned* __restrict__ bin_ofs,
                                                const unsigned* __restrict__ recs,
                                                const float* __restrict__ pos,
                                                const float* __restrict__ pemb,
                                                float* __restrict__ out) {
    __shared__ float tile[2][16 * TP];      // 2 x 16.6 KB

    // XCD-chunked swizzle: each XCD owns a contiguous bin super-range.
    const int b    = blockIdx.x;
    const int swz  = (b & 7) * (NBLK >> 3) + (b >> 3);
    const int bin0 = swz * BPB;

    const int tid = threadIdx.x;
    const int w   = tid >> 6;
    const int l   = tid & 63;
    const int o4  = (tid & 3) << 2;         // x-offset group for staging
    const int csub = tid >> 2;              // 0..63 channel sub-index

    // point_emb rows for this lane's 4 channels, hoisted to registers
    const float4 te0 = *reinterpret_cast<const float4*>(pemb + 4 * l);
    const float4 te1 = *reinterpret_cast<const float4*>(pemb + C_ + 4 * l);

    auto linebase = [](int bin) -> size_t {
        return ((size_t)(bin >> 8) << 12) | ((size_t)((bin >> 2) & 63) << 6) |
               ((size_t)(bin & 3) << 4);
    };

    float4 rv0, rv1, rv2, rv3;
    // prologue: load + stage bin0 into tile[0]
    {
        const size_t lb = linebase(bin0);
        rv0 = *reinterpret_cast<const float4*>(pos + (size_t)(  0 + csub) * CELLS + lb + o4);
        rv1 = *reinterpret_cast<const float4*>(pos + (size_t)( 64 + csub) * CELLS + lb + o4);
        rv2 = *reinterpret_cast<const float4*>(pos + (size_t)(128 + csub) * CELLS + lb + o4);
        rv3 = *reinterpret_cast<const float4*>(pos + (size_t)(192 + csub) * CELLS + lb + o4);
        float* t0 = tile[0];
        t0[(o4 + 0) * TP +   0 + csub] = rv0.x; t0[(o4 + 1) * TP +   0 + csub] = rv0.y;
        t0[(o4 + 2) * TP +   0 + csub] = rv0.z; t0[(o4 + 3) * TP +   0 + csub] = rv0.w;
        t0[(o4 + 0) * TP +  64 + csub] = rv1.x; t0[(o4 + 1) * TP +  64 + csub] = rv1.y;
        t0[(o4 + 2) * TP +  64 + csub] = rv1.z; t0[(o4 + 3) * TP +  64 + csub] = rv1.w;
        t0[(o4 + 0) * TP + 128 + csub] = rv2.x; t0[(o4 + 1) * TP + 128 + csub] = rv2.y;
        t0[(o4 + 2) * TP + 128 + csub] = rv2.z; t0[(o4 + 3) * TP + 128 + csub] = rv2.w;
        t0[(o4 + 0) * TP + 192 + csub] = rv3.x; t0[(o4 + 1) * TP + 192 + csub] = rv3.y;
        t0[(o4 + 2) * TP + 192 + csub] = rv3.z; t0[(o4 + 3) * TP + 192 + csub] = rv3.w;
    }

    for (int k = 0; k < BPB; ++k) {
        const int cur = k & 1;
        // issue next bin's loads (stay in flight across barrier + phase 2)
        if (k + 1 < BPB) {
            const size_t lb = linebase(bin0 + k + 1);
            rv0 = *reinterpret_cast<const float4*>(pos + (size_t)(  0 + csub) * CELLS + lb + o4);
            rv1 = *reinterpret_cast<const float4*>(pos + (size_t)( 64 + csub) * CELLS + lb + o4);
            rv2 = *reinterpret_cast<const float4*>(pos + (size_t)(128 + csub) * CELLS + lb + o4);
            rv3 = *reinterpret_cast<const float4*>(pos + (size_t)(192 + csub) * CELLS + lb + o4);
        }
        __syncthreads();   // tile[cur] fully staged; prev phase-2 done

        // phase 2: one wave per point, coalesced 1-KB row store
        const int bin = bin0 + k;
        const unsigned start = bin_ofs[bin];
        const unsigned end   = bin_ofs[bin + 1];
        const float* tcur = tile[cur];
        for (unsigned i = start + w; i < end; i += 4) {
            const unsigned rec = recs[i];            // wave-uniform broadcast
            const unsigned p   = rec & 0x1FFFFu;
            const unsigned o   = rec >> 18;
            const float4 te = ((rec >> 17) & 1u) ? te1 : te0;
            const float4 v  = *reinterpret_cast<const float4*>(tcur + o * TP + 4 * l);
            f32x4 rr;
            rr.x = v.x + te.x; rr.y = v.y + te.y; rr.z = v.z + te.z; rr.w = v.w + te.w;
            __builtin_nontemporal_store(rr,
                reinterpret_cast<f32x4*>(out + (size_t)p * C_ + 4 * l));
        }

        // write the prefetched bin into the other buffer (WAR safe: last
        // reader of tile[cur^1] finished before the barrier above)
        if (k + 1 < BPB) {
            float* tn = tile[cur ^ 1];
            tn[(o4 + 0) * TP +   0 + csub] = rv0.x; tn[(o4 + 1) * TP +   0 + csub] = rv0.y;
            tn[(o4 + 2) * TP +   0 + csub] = rv0.z; tn[(o4 + 3) * TP +   0 + csub] = rv0.w;
            tn[(o4 + 0) * TP +  64 + csub] = rv1.x; tn[(o4 + 1) * TP +  64 + csub] = rv1.y;
            tn[(o4 + 2) * TP +  64 + csub] = rv1.z; tn[(o4 + 3) * TP +  64 + csub] = rv1.w;
            tn[(o4 + 0) * TP + 128 + csub] = rv2.x; tn[(o4 + 1) * TP + 128 + csub] = rv2.y;
            tn[(o4 + 2) * TP + 128 + csub] = rv2.z; tn[(o4 + 3) * TP + 128 + csub] = rv2.w;
            tn[(o4 + 0) * TP + 192 + csub] = rv3.x; tn[(o4 + 1) * TP + 192 + csub] = rv3.y;
            tn[(o4 + 2) * TP + 192 + csub] = rv3.z; tn[(o4 + 3) * TP + 192 + csub] = rv3.w;
        }
    }
}

// ---- fallback if ws too small ----
__global__ __launch_bounds__(256) void k_naive(const float* __restrict__ points,
                                               const int* __restrict__ labels,
                                               const float* __restrict__ pos,
                                               const float* __restrict__ pemb,
                                               float* __restrict__ out) {
    const int t    = blockIdx.x * blockDim.x + threadIdx.x;
    const int p    = t >> 6;
    const int lane = t & 63;
    const int c4   = lane << 2;
    if (p >= PTS) return;
    int zi = clamp63(points[p * 3 + 0]);
    int yi = clamp63(points[p * 3 + 1]);
    int xi = clamp63(points[p * 3 + 2]);
    const int cell = (zi << 12) | (yi << 6) | xi;
    const int lab  = labels[p];
    const float4 te = *reinterpret_cast<const float4*>(pemb + lab * C_ + c4);
    const float* g = pos + cell;
    float4 r;
    r.x = g[(c4 + 0) * CELLS] + te.x;
    r.y = g[(c4 + 1) * CELLS] + te.y;
    r.z = g[(c4 + 2) * CELLS] + te.z;
    r.w = g[(c4 + 3) * CELLS] + te.w;
    *reinterpret_cast<float4*>(out + p * C_ + c4) = r;
}

extern "C" void kernel_launch(void* const* d_in, const int* in_sizes, int n_in,
                              void* d_out, int out_size, void* d_ws, size_t ws_size,
                              hipStream_t stream) {
    const float* points = (const float*)d_in[0];
    const int*   labels = (const int*)d_in[1];
    const float* pos    = (const float*)d_in[2];
    const float* pemb   = (const float*)d_in[3];
    float*       out    = (float*)d_out;

    // ws layout: hist[NBINS] | cursor[NBINS] | bin_ofs[NBINS+1] | recs[PTS]
    const size_t need = (size_t)(NBINS * 3 + 1 + PTS) * sizeof(unsigned);
    if (ws_size < need) {
        const int total = PTS * 64;
        k_naive<<<(total + 255) / 256, 256, 0, stream>>>(points, labels, pos, pemb, out);
        return;
    }
    unsigned* hist    = (unsigned*)d_ws;
    unsigned* cursor  = hist + NBINS;
    unsigned* bin_ofs = cursor + NBINS;
    unsigned* recs    = bin_ofs + NBINS + 1;

    k_zero<<<(NBINS + 255) / 256, 256, 0, stream>>>(hist);
    k_hist<<<(PTS + 255) / 256, 256, 0, stream>>>(points, hist);
    k_scan<<<1, 1024, 0, stream>>>(hist, cursor, bin_ofs);
    k_scatter<<<(PTS + 255) / 256, 256, 0, stream>>>(points, labels, cursor, recs);
    k_gather<<<NBLK, 256, 0, stream>>>(bin_ofs, recs, pos, pemb, out);
}

// Round 8
// 97.912 us; speedup vs baseline: 2.3106x; 1.1114x over previous
//
#include <hip/hip_runtime.h>

// FastSAM3DPromptEncoder: out[b,n,c] = pos_embed[0,c,z,y,x] + point_emb[labels[b,n],c]
// (z,y,x) = clamp(trunc(points[b,n,:]), 0, 63).
//
// Counting-sort points by 64-B-line key (z,y,x>>4) into fixed-capacity bin
// segments (single atomic scatter pass, no histogram/scan kernels), then
// bin-centric gather: 8 bins/block, double-buffered LDS tile, software-
// pipelined staging. Padded LDS stride (260) = conflict-free.

constexpr int B_ = 32;
constexpr int N_ = 4096;
constexpr int C_ = 256;
constexpr int GD = 64;
constexpr int PTS = B_ * N_;               // 131072
constexpr int CELLS = GD * GD * GD;        // 262144 (channel stride)
constexpr int NBINS = GD * GD * (GD / 16); // 16384 line keys
constexpr int CAP = 64;                    // slots per bin (avg fill 8; P(>64)~1e-33)
constexpr int BPB = 8;                     // bins per block
constexpr int NBLK = NBINS / BPB;          // 2048 blocks
constexpr int TP = 260;                    // padded tile row stride (floats)

typedef float f32x4 __attribute__((ext_vector_type(4)));  // native vec for nt-store

__device__ __forceinline__ int clamp63(float v) {
    int i = (int)v;
    return min(max(i, 0), GD - 1);
}

// ---- K1: scatter packed point records into fixed-capacity bin segments ----
// rec = p (17b) | lab (1b @17) | x&15 (4b @18)
__global__ __launch_bounds__(256) void k_scatter(const float* __restrict__ points,
                                                 const int* __restrict__ labels,
                                                 unsigned* __restrict__ counts,
                                                 unsigned* __restrict__ recs,
                                                 const float* __restrict__ pos,
                                                 const float* __restrict__ pemb,
                                                 float* __restrict__ out) {
    int p = blockIdx.x * blockDim.x + threadIdx.x;
    if (p >= PTS) return;
    int zi = clamp63(points[p * 3 + 0]);
    int yi = clamp63(points[p * 3 + 1]);
    int xi = clamp63(points[p * 3 + 2]);
    int key = (zi << 8) | (yi << 2) | (xi >> 4);
    int lab = labels[p];
    unsigned slot = atomicAdd(&counts[key], 1u);
    if (slot < CAP) {
        recs[key * CAP + slot] =
            (unsigned)p | ((unsigned)lab << 17) | ((unsigned)(xi & 15) << 18);
    } else {
        // statistically unreachable overflow: write this point's row directly
        const int cell = (zi << 12) | (yi << 6) | xi;
        for (int c = 0; c < C_; ++c)
            out[(size_t)p * C_ + c] = pos[(size_t)c * CELLS + cell] + pemb[lab * C_ + c];
    }
}

// ---- K2: pipelined bin-centric gather. 8 bins/block, dbuf LDS ----
__global__ __launch_bounds__(256) void k_gather(const unsigned* __restrict__ counts,
                                                const unsigned* __restrict__ recs,
                                                const float* __restrict__ pos,
                                                const float* __restrict__ pemb,
                                                float* __restrict__ out) {
    __shared__ float tile[2][16 * TP];      // 2 x 16.6 KB

    // XCD-chunked swizzle: each XCD owns a contiguous bin super-range.
    const int b    = blockIdx.x;
    const int swz  = (b & 7) * (NBLK >> 3) + (b >> 3);
    const int bin0 = swz * BPB;

    const int tid  = threadIdx.x;
    const int w    = tid >> 6;
    const int l    = tid & 63;
    const int o4   = (tid & 3) << 2;        // x-offset group for staging
    const int csub = tid >> 2;              // 0..63 channel sub-index

    // point_emb rows for this lane's 4 channels, hoisted to registers
    const float4 te0 = *reinterpret_cast<const float4*>(pemb + 4 * l);
    const float4 te1 = *reinterpret_cast<const float4*>(pemb + C_ + 4 * l);

    auto linebase = [](int bin) -> size_t {
        return ((size_t)(bin >> 8) << 12) | ((size_t)((bin >> 2) & 63) << 6) |
               ((size_t)(bin & 3) << 4);
    };

    float4 rv0, rv1, rv2, rv3;
    // prologue: load + stage bin0 into tile[0]
    {
        const size_t lb = linebase(bin0);
        rv0 = *reinterpret_cast<const float4*>(pos + (size_t)(  0 + csub) * CELLS + lb + o4);
        rv1 = *reinterpret_cast<const float4*>(pos + (size_t)( 64 + csub) * CELLS + lb + o4);
        rv2 = *reinterpret_cast<const float4*>(pos + (size_t)(128 + csub) * CELLS + lb + o4);
        rv3 = *reinterpret_cast<const float4*>(pos + (size_t)(192 + csub) * CELLS + lb + o4);
        float* t0 = tile[0];
        t0[(o4 + 0) * TP +   0 + csub] = rv0.x; t0[(o4 + 1) * TP +   0 + csub] = rv0.y;
        t0[(o4 + 2) * TP +   0 + csub] = rv0.z; t0[(o4 + 3) * TP +   0 + csub] = rv0.w;
        t0[(o4 + 0) * TP +  64 + csub] = rv1.x; t0[(o4 + 1) * TP +  64 + csub] = rv1.y;
        t0[(o4 + 2) * TP +  64 + csub] = rv1.z; t0[(o4 + 3) * TP +  64 + csub] = rv1.w;
        t0[(o4 + 0) * TP + 128 + csub] = rv2.x; t0[(o4 + 1) * TP + 128 + csub] = rv2.y;
        t0[(o4 + 2) * TP + 128 + csub] = rv2.z; t0[(o4 + 3) * TP + 128 + csub] = rv2.w;
        t0[(o4 + 0) * TP + 192 + csub] = rv3.x; t0[(o4 + 1) * TP + 192 + csub] = rv3.y;
        t0[(o4 + 2) * TP + 192 + csub] = rv3.z; t0[(o4 + 3) * TP + 192 + csub] = rv3.w;
    }

    for (int k = 0; k < BPB; ++k) {
        const int cur = k & 1;
        // issue next bin's loads (stay in flight across barrier + phase 2)
        if (k + 1 < BPB) {
            const size_t lb = linebase(bin0 + k + 1);
            rv0 = *reinterpret_cast<const float4*>(pos + (size_t)(  0 + csub) * CELLS + lb + o4);
            rv1 = *reinterpret_cast<const float4*>(pos + (size_t)( 64 + csub) * CELLS + lb + o4);
            rv2 = *reinterpret_cast<const float4*>(pos + (size_t)(128 + csub) * CELLS + lb + o4);
            rv3 = *reinterpret_cast<const float4*>(pos + (size_t)(192 + csub) * CELLS + lb + o4);
        }
        __syncthreads();   // tile[cur] fully staged; prev phase-2 done

        // phase 2: one wave per point, coalesced 1-KB row store
        const int bin = bin0 + k;
        const unsigned cnt   = min(counts[bin], (unsigned)CAP);
        const unsigned start = (unsigned)bin * CAP;
        const unsigned end   = start + cnt;
        const float* tcur = tile[cur];
        for (unsigned i = start + w; i < end; i += 4) {
            const unsigned rec = recs[i];            // wave-uniform broadcast
            const unsigned p   = rec & 0x1FFFFu;
            const unsigned o   = rec >> 18;
            const float4 te = ((rec >> 17) & 1u) ? te1 : te0;
            const float4 v  = *reinterpret_cast<const float4*>(tcur + o * TP + 4 * l);
            f32x4 rr;
            rr.x = v.x + te.x; rr.y = v.y + te.y; rr.z = v.z + te.z; rr.w = v.w + te.w;
            __builtin_nontemporal_store(rr,
                reinterpret_cast<f32x4*>(out + (size_t)p * C_ + 4 * l));
        }

        // write the prefetched bin into the other buffer (WAR safe: last
        // reader of tile[cur^1] finished before the barrier above)
        if (k + 1 < BPB) {
            float* tn = tile[cur ^ 1];
            tn[(o4 + 0) * TP +   0 + csub] = rv0.x; tn[(o4 + 1) * TP +   0 + csub] = rv0.y;
            tn[(o4 + 2) * TP +   0 + csub] = rv0.z; tn[(o4 + 3) * TP +   0 + csub] = rv0.w;
            tn[(o4 + 0) * TP +  64 + csub] = rv1.x; tn[(o4 + 1) * TP +  64 + csub] = rv1.y;
            tn[(o4 + 2) * TP +  64 + csub] = rv1.z; tn[(o4 + 3) * TP +  64 + csub] = rv1.w;
            tn[(o4 + 0) * TP + 128 + csub] = rv2.x; tn[(o4 + 1) * TP + 128 + csub] = rv2.y;
            tn[(o4 + 2) * TP + 128 + csub] = rv2.z; tn[(o4 + 3) * TP + 128 + csub] = rv2.w;
            tn[(o4 + 0) * TP + 192 + csub] = rv3.x; tn[(o4 + 1) * TP + 192 + csub] = rv3.y;
            tn[(o4 + 2) * TP + 192 + csub] = rv3.z; tn[(o4 + 3) * TP + 192 + csub] = rv3.w;
        }
    }
}

// ---- fallback if ws too small ----
__global__ __launch_bounds__(256) void k_naive(const float* __restrict__ points,
                                               const int* __restrict__ labels,
                                               const float* __restrict__ pos,
                                               const float* __restrict__ pemb,
                                               float* __restrict__ out) {
    const int t    = blockIdx.x * blockDim.x + threadIdx.x;
    const int p    = t >> 6;
    const int lane = t & 63;
    const int c4   = lane << 2;
    if (p >= PTS) return;
    int zi = clamp63(points[p * 3 + 0]);
    int yi = clamp63(points[p * 3 + 1]);
    int xi = clamp63(points[p * 3 + 2]);
    const int cell = (zi << 12) | (yi << 6) | xi;
    const int lab  = labels[p];
    const float4 te = *reinterpret_cast<const float4*>(pemb + lab * C_ + c4);
    const float* g = pos + cell;
    float4 r;
    r.x = g[(c4 + 0) * CELLS] + te.x;
    r.y = g[(c4 + 1) * CELLS] + te.y;
    r.z = g[(c4 + 2) * CELLS] + te.z;
    r.w = g[(c4 + 3) * CELLS] + te.w;
    *reinterpret_cast<float4*>(out + p * C_ + c4) = r;
}

extern "C" void kernel_launch(void* const* d_in, const int* in_sizes, int n_in,
                              void* d_out, int out_size, void* d_ws, size_t ws_size,
                              hipStream_t stream) {
    const float* points = (const float*)d_in[0];
    const int*   labels = (const int*)d_in[1];
    const float* pos    = (const float*)d_in[2];
    const float* pemb   = (const float*)d_in[3];
    float*       out    = (float*)d_out;

    // ws layout: counts[NBINS] | recs[NBINS*CAP]
    const size_t need = (size_t)(NBINS + NBINS * CAP) * sizeof(unsigned);
    if (ws_size < need) {
        const int total = PTS * 64;
        k_naive<<<(total + 255) / 256, 256, 0, stream>>>(points, labels, pos, pemb, out);
        return;
    }
    unsigned* counts = (unsigned*)d_ws;
    unsigned* recs   = counts + NBINS;

    hipMemsetAsync(counts, 0, NBINS * sizeof(unsigned), stream);
    k_scatter<<<(PTS + 255) / 256, 256, 0, stream>>>(points, labels, counts, recs,
                                                     pos, pemb, out);
    k_gather<<<NBLK, 256, 0, stream>>>(counts, recs, pos, pemb, out);
}